// Round 5
// baseline (735.366 us; speedup 1.0000x reference)
//
#include <hip/hip_runtime.h>
#include <math.h>

#define B_      16
#define C_      512
#define HW_     4096
#define P_      1024
#define EPSN    1e-4f
#define TEMP_   20.0f
#define THRESH_ 0.95f
#define NEGINF_ -1e9f
#define TIE_THR 1e-3f

#define PRED_OFF   0
#define ASSIGN_OFF 65536
#define GRID_OFF   131072

#define NPIX    65536          // B_*HW_
#define NSLICE  16             // 1024 n / 64 per wave-slice

typedef short short8 __attribute__((ext_vector_type(8)));
typedef float f32x16 __attribute__((ext_vector_type(16)));

__device__ inline unsigned short f2bf(float f) {
    unsigned u = __float_as_uint(f);
    unsigned r = u + 0x7fffu + ((u >> 16) & 1u);
    return (unsigned short)(r >> 16);
}
__device__ inline float bf2f(unsigned short h) {
    return __uint_as_float((unsigned)h << 16);
}

// ---------------- pool sup_y -> proto_grid + valid ----------------
__global__ void pool_y_kernel(const float* __restrict__ sup_y,
                              float* __restrict__ out_grid,
                              float* __restrict__ validf) {
    int p = blockIdx.x * blockDim.x + threadIdx.x;
    if (p >= P_) return;
    int b = p >> 6, cell = p & 63, gy = cell >> 3, gx = cell & 7;
    const float* base = sup_y + b * HW_ + gy * 8 * 64 + gx * 8;
    float s = 0.f;
    #pragma unroll
    for (int r = 0; r < 8; ++r)
        #pragma unroll
        for (int c = 0; c < 8; ++c) s += base[r * 64 + c];
    float avg = s * (1.0f / 64.0f);
    out_grid[p] = (avg < THRESH_) ? 0.0f : avg;
    validf[p]   = (avg > THRESH_) ? 1.0f : 0.0f;
}

// ---------------- pool sup_x -> pooledT[c][p], 4 channels/block ----------------
__global__ __launch_bounds__(256) void pool_x_kernel(const float* __restrict__ sup_x,
                                                     float* __restrict__ pooledT) {
    int blk = blockIdx.x * 4 + (threadIdx.x >> 6);   // b*C_ + c
    int b = blk >> 9, c = blk & 511;
    int lane = threadIdx.x & 63;
    const float* base = sup_x + (size_t)(b * C_ + c) * HW_;
    float acc[8];
    #pragma unroll
    for (int g = 0; g < 8; ++g) acc[g] = 0.f;
    #pragma unroll
    for (int h = 0; h < 64; ++h) {
        float v = base[h * 64 + lane];
        acc[h >> 3] += v;
    }
    #pragma unroll
    for (int g = 0; g < 8; ++g) {
        acc[g] += __shfl_xor(acc[g], 1);
        acc[g] += __shfl_xor(acc[g], 2);
        acc[g] += __shfl_xor(acc[g], 4);
    }
    if ((lane & 7) == 0) {
        int gx = lane >> 3;
        #pragma unroll
        for (int gy = 0; gy < 8; ++gy) {
            int p = b * 64 + gy * 8 + gx;
            pooledT[c * P_ + p] = acc[gy] * (1.0f / 64.0f);
        }
    }
}

// ---------------- per-proto 1/max(norm,eps): one wave per proto ----------------
__global__ __launch_bounds__(256) void proto_rnorm_kernel(const float* __restrict__ pooledT,
                                                          const float* __restrict__ validf,
                                                          float* __restrict__ rnv) {
    int p = blockIdx.x * 4 + (threadIdx.x >> 6);
    int lane = threadIdx.x & 63;
    double ss = 0.0;
    #pragma unroll
    for (int i = 0; i < 8; ++i) {
        double v = (double)pooledT[(lane + i * 64) * P_ + p];
        ss += v * v;
    }
    #pragma unroll
    for (int off = 1; off < 64; off <<= 1) ss += __shfl_xor(ss, off);
    if (lane == 0) {
        float rn = 1.0f / fmaxf((float)sqrt(ss), EPSN);
        rnv[p] = (validf[p] > 0.5f) ? rn : 0.0f;
    }
}

// ---------------- pack protos: Bp{h,l}[(sk*2+kh)*1024 + n][8] bf16 ----------------
__global__ __launch_bounds__(256) void pack_b_kernel(const float* __restrict__ pooledT,
                                                     short* __restrict__ Bph,
                                                     short* __restrict__ Bpl) {
    int t = blockIdx.x * 256 + threadIdx.x;   // 0..32767
    int sk = t >> 10, n = t & 1023;
    #pragma unroll
    for (int kh = 0; kh < 2; ++kh) {
        unsigned short vh[8], vl[8];
        #pragma unroll
        for (int j = 0; j < 8; ++j) {
            float p = pooledT[(sk * 16 + kh * 8 + j) * P_ + n];
            unsigned short h = f2bf(p);
            vh[j] = h;
            vl[j] = f2bf(p - bf2f(h));
        }
        uint4 uh, ul;
        uh.x = (unsigned)vh[0] | ((unsigned)vh[1] << 16);
        uh.y = (unsigned)vh[2] | ((unsigned)vh[3] << 16);
        uh.z = (unsigned)vh[4] | ((unsigned)vh[5] << 16);
        uh.w = (unsigned)vh[6] | ((unsigned)vh[7] << 16);
        ul.x = (unsigned)vl[0] | ((unsigned)vl[1] << 16);
        ul.y = (unsigned)vl[2] | ((unsigned)vl[3] << 16);
        ul.z = (unsigned)vl[4] | ((unsigned)vl[5] << 16);
        ul.w = (unsigned)vl[6] | ((unsigned)vl[7] << 16);
        size_t off = ((size_t)(sk * 2 + kh) * 1024 + n) * 8;
        *(uint4*)&Bph[off] = uh;
        *(uint4*)&Bpl[off] = ul;
    }
}

// ---------------- split qry into hi/lo bf16, A-fragment packed; also rq ----------
// Ap{h,l}[(sk*2+kh)*NPIX + m][8] , element c = sk*16 + kh*8 + j
__global__ __launch_bounds__(256) void qsplit_kernel(const float* __restrict__ qry,
                                                     short* __restrict__ Aph,
                                                     short* __restrict__ Apl,
                                                     float* __restrict__ rq) {
    __shared__ float ssb[4][64];
    int blk = blockIdx.x;                 // 0..1023
    int b = blk >> 6, ch = blk & 63;
    int tid = threadIdx.x, w = tid >> 6, lane = tid & 63;
    int hw = ch * 64 + lane;
    int m = b * HW_ + hw;
    const float* qb = qry + (size_t)b * (C_ * HW_) + hw;
    float ss = 0.f;
    for (int i = 0; i < 16; ++i) {
        int g = w + i * 4;                // k8-group 0..63
        int c0 = g * 8;
        unsigned short vh[8], vl[8];
        #pragma unroll
        for (int j = 0; j < 8; ++j) {
            float q = qb[(size_t)(c0 + j) * HW_];
            ss += q * q;
            unsigned short h = f2bf(q);
            vh[j] = h;
            vl[j] = f2bf(q - bf2f(h));
        }
        uint4 uh, ul;
        uh.x = (unsigned)vh[0] | ((unsigned)vh[1] << 16);
        uh.y = (unsigned)vh[2] | ((unsigned)vh[3] << 16);
        uh.z = (unsigned)vh[4] | ((unsigned)vh[5] << 16);
        uh.w = (unsigned)vh[6] | ((unsigned)vh[7] << 16);
        ul.x = (unsigned)vl[0] | ((unsigned)vl[1] << 16);
        ul.y = (unsigned)vl[2] | ((unsigned)vl[3] << 16);
        ul.z = (unsigned)vl[4] | ((unsigned)vl[5] << 16);
        ul.w = (unsigned)vl[6] | ((unsigned)vl[7] << 16);
        size_t off = ((size_t)g * NPIX + m) * 8;   // g == sk*2+kh
        *(uint4*)&Aph[off] = uh;
        *(uint4*)&Apl[off] = ul;
    }
    ssb[w][lane] = ss;
    __syncthreads();
    if (tid < 64) {
        float s = ssb[0][tid] + ssb[1][tid] + ssb[2][tid] + ssb[3][tid];
        rq[b * HW_ + ch * 64 + tid] = 1.0f / fmaxf(sqrtf(s), EPSN);
    }
}

// ---------------- barrier-free MFMA GEMM + per-wave slice reduction ----------
// grid 4096 = 512 m-blocks x 8 n-blocks; 256 threads = 4 waves (2m x 2n).
// wave tile: 2 m-subtiles x 2 n-subtiles of 32x32; acc = 64 AGPRs.
// part[(slice*6+f)*NPIX + pix] : {v1, v2, n1, n2, se, sv}
__global__ __launch_bounds__(256, 4) void gemm_kernel(
        const short* __restrict__ Aph, const short* __restrict__ Apl,
        const short* __restrict__ Bph, const short* __restrict__ Bpl,
        const float* __restrict__ rnv, const float* __restrict__ rq,
        float* __restrict__ part) {
    __shared__ float stg[4][64][6];

    int idx = blockIdx.x;
    int bn = idx >> 9;                 // 0..7
    int bm = idx & 511;                // 0..511
    int tid = threadIdx.x;
    int w = tid >> 6, lane = tid & 63;
    int hl = lane & 31, half = lane >> 5;
    int wm = w >> 1, wn = w & 1;

    int mwb = bm * 128 + wm * 64;      // wave pixel base (64 pixels)
    int nwb = bn * 128 + wn * 64;      // wave proto base (64 protos)
    int slice = bn * 2 + wn;           // 0..15

    const short* pAh = Aph + ((size_t)half * NPIX + mwb + hl) * 8;
    const short* pAl = Apl + ((size_t)half * NPIX + mwb + hl) * 8;
    const short* pBh = Bph + ((size_t)half * 1024 + nwb + hl) * 8;
    const short* pBl = Bpl + ((size_t)half * 1024 + nwb + hl) * 8;

    f32x16 zero16 = {0.f,0.f,0.f,0.f,0.f,0.f,0.f,0.f,0.f,0.f,0.f,0.f,0.f,0.f,0.f,0.f};
    f32x16 acc[2][2];
    acc[0][0] = zero16; acc[0][1] = zero16; acc[1][0] = zero16; acc[1][1] = zero16;

    for (int sk = 0; sk < 32; ++sk) {
        short8 ah0 = *(const short8*)(pAh);
        short8 ah1 = *(const short8*)(pAh + 256);
        short8 al0 = *(const short8*)(pAl);
        short8 al1 = *(const short8*)(pAl + 256);
        short8 bh0 = *(const short8*)(pBh);
        short8 bh1 = *(const short8*)(pBh + 256);
        short8 bl0 = *(const short8*)(pBl);
        short8 bl1 = *(const short8*)(pBl + 256);

        acc[0][0] = __builtin_amdgcn_mfma_f32_32x32x16_bf16(ah0, bh0, acc[0][0], 0, 0, 0);
        acc[0][1] = __builtin_amdgcn_mfma_f32_32x32x16_bf16(ah0, bh1, acc[0][1], 0, 0, 0);
        acc[1][0] = __builtin_amdgcn_mfma_f32_32x32x16_bf16(ah1, bh0, acc[1][0], 0, 0, 0);
        acc[1][1] = __builtin_amdgcn_mfma_f32_32x32x16_bf16(ah1, bh1, acc[1][1], 0, 0, 0);
        acc[0][0] = __builtin_amdgcn_mfma_f32_32x32x16_bf16(al0, bh0, acc[0][0], 0, 0, 0);
        acc[0][1] = __builtin_amdgcn_mfma_f32_32x32x16_bf16(al0, bh1, acc[0][1], 0, 0, 0);
        acc[1][0] = __builtin_amdgcn_mfma_f32_32x32x16_bf16(al1, bh0, acc[1][0], 0, 0, 0);
        acc[1][1] = __builtin_amdgcn_mfma_f32_32x32x16_bf16(al1, bh1, acc[1][1], 0, 0, 0);
        acc[0][0] = __builtin_amdgcn_mfma_f32_32x32x16_bf16(ah0, bl0, acc[0][0], 0, 0, 0);
        acc[0][1] = __builtin_amdgcn_mfma_f32_32x32x16_bf16(ah0, bl1, acc[0][1], 0, 0, 0);
        acc[1][0] = __builtin_amdgcn_mfma_f32_32x32x16_bf16(ah1, bl0, acc[1][0], 0, 0, 0);
        acc[1][1] = __builtin_amdgcn_mfma_f32_32x32x16_bf16(ah1, bl1, acc[1][1], 0, 0, 0);

        pAh += NPIX * 16; pAl += NPIX * 16;
        pBh += 1024 * 16; pBl += 1024 * 16;
    }

    // ---- per-wave slice reduction (64 n per wave) ----
    float rq_l = rq[mwb + lane];
    float rn0 = rnv[nwb + hl];
    float rn1 = rnv[nwb + 32 + hl];
    int n0 = nwb + hl, n1i = nwb + 32 + hl;

    #pragma unroll
    for (int mt = 0; mt < 2; ++mt) {
        #pragma unroll
        for (int r = 0; r < 16; ++r) {
            int rowl = mt * 32 + (r & 3) + 8 * (r >> 2) + 4 * half;  // 0..63
            float scale = __shfl(rq_l, rowl) * TEMP_;
            float d0 = acc[mt][0][r] * rn0 * scale;
            float d1 = acc[mt][1][r] * rn1 * scale;
            float lg0 = (rn0 > 0.f) ? d0 : NEGINF_;
            float lg1 = (rn1 > 0.f) ? d1 : NEGINF_;
            // per-lane top2 of the two candidates (n0 < n1i always)
            float v1, v2; int n1, n2;
            if (lg1 > lg0) { v1 = lg1; n1 = n1i; v2 = lg0; n2 = n0; }
            else           { v1 = lg0; n1 = n0;  v2 = lg1; n2 = n1i; }
            // butterfly top2 over the 32-lane half (offsets < 32)
            #pragma unroll
            for (int off = 1; off < 32; off <<= 1) {
                float ov1 = __shfl_xor(v1, off), ov2 = __shfl_xor(v2, off);
                int   on1 = __shfl_xor(n1, off), on2 = __shfl_xor(n2, off);
                if (ov1 > v1 || (ov1 == v1 && on1 < n1)) {
                    if (v1 > ov2 || (v1 == ov2 && n1 < on2)) { v2 = v1; n2 = n1; }
                    else                                     { v2 = ov2; n2 = on2; }
                    v1 = ov1; n1 = on1;
                } else {
                    if (ov1 > v2 || (ov1 == v2 && on1 < n2)) { v2 = ov1; n2 = on1; }
                }
            }
            float e0 = __expf(lg0 - v1), e1 = __expf(lg1 - v1);
            float se = e0 + e1;
            float sv = e0 * d0 + e1 * d1;
            #pragma unroll
            for (int off = 1; off < 32; off <<= 1) {
                se += __shfl_xor(se, off);
                sv += __shfl_xor(sv, off);
            }
            if (hl == 0) {
                stg[w][rowl][0] = v1;
                stg[w][rowl][1] = v2;
                stg[w][rowl][2] = __int_as_float(n1);
                stg[w][rowl][3] = __int_as_float(n2);
                stg[w][rowl][4] = se;
                stg[w][rowl][5] = sv;
            }
        }
    }
    // same-wave LDS write->read (compiler inserts lgkmcnt wait); coalesced store
    #pragma unroll
    for (int f = 0; f < 6; ++f)
        part[(size_t)(slice * 6 + f) * NPIX + mwb + lane] = stg[w][lane][f];
}

// ---------------- merge slices + pred + argmax (+ fp64 tie refinement) --------
__global__ __launch_bounds__(256) void merge_kernel(const float* __restrict__ part,
                                                    const float* __restrict__ qry,
                                                    const float* __restrict__ pooledT,
                                                    float* __restrict__ out) {
    __shared__ int qpix[256];
    __shared__ int qn[256];
    __shared__ int qcnt;
    int tid = threadIdx.x;
    if (tid == 0) qcnt = 0;
    __syncthreads();

    int pix = blockIdx.x * 256 + tid;
    float v1 = -3e38f, v2 = -3e38f, se = 0.f, sv = 0.f;
    int n1 = P_, n2 = P_;
    for (int s = 0; s < NSLICE; ++s) {
        const float* ps = part + (size_t)s * 6 * NPIX + pix;
        float a1  = ps[0];
        float a2  = ps[(size_t)1 * NPIX];
        int   an1 = __float_as_int(ps[(size_t)2 * NPIX]);
        int   an2 = __float_as_int(ps[(size_t)3 * NPIX]);
        float ase = ps[(size_t)4 * NPIX];
        float asv = ps[(size_t)5 * NPIX];
        float nv1, nv2; int nn1, nn2;
        if (a1 > v1 || (a1 == v1 && an1 < n1)) {
            nv1 = a1; nn1 = an1;
            if (v1 > a2 || (v1 == a2 && n1 < an2)) { nv2 = v1; nn2 = n1; }
            else                                   { nv2 = a2; nn2 = an2; }
        } else {
            nv1 = v1; nn1 = n1;
            if (a1 > v2 || (a1 == v2 && an1 < n2)) { nv2 = a1; nn2 = an1; }
            else                                   { nv2 = v2; nn2 = n2; }
        }
        float fa = __expf(v1 - nv1), fb = __expf(a1 - nv1);
        se = se * fa + ase * fb;
        sv = sv * fa + asv * fb;
        v1 = nv1; n1 = nn1; v2 = nv2; n2 = nn2;
    }
    out[PRED_OFF + pix]   = sv / se;
    out[ASSIGN_OFF + pix] = (float)n1;
    if (n2 < P_ && (v1 - v2) < TIE_THR) {
        int pos = atomicAdd(&qcnt, 1);
        qpix[pos] = pix;
        qn[pos] = n1 | (n2 << 16);
    }
    __syncthreads();

    int w = tid >> 6, lane = tid & 63;
    int cnt = qcnt;
    for (int i = w; i < cnt; i += 4) {
        int pixq = qpix[i];
        int nn = qn[i];
        int c1 = nn & 0xffff, c2 = nn >> 16;
        int b = pixq >> 12, hw = pixq & 4095;
        const float* qcol = qry + (size_t)b * (C_ * HW_) + hw;
        double d1 = 0.0, d2 = 0.0, s1 = 0.0, s2 = 0.0;
        for (int cc = lane; cc < C_; cc += 64) {
            double qv = (double)qcol[(size_t)cc * HW_];
            double p1 = (double)pooledT[cc * P_ + c1];
            double p2 = (double)pooledT[cc * P_ + c2];
            d1 += qv * p1; d2 += qv * p2;
            s1 += p1 * p1; s2 += p2 * p2;
        }
        #pragma unroll
        for (int off = 1; off < 64; off <<= 1) {
            d1 += __shfl_xor(d1, off); d2 += __shfl_xor(d2, off);
            s1 += __shfl_xor(s1, off); s2 += __shfl_xor(s2, off);
        }
        double f1 = d1 / fmax(sqrt(s1), (double)EPSN);
        double f2 = d2 / fmax(sqrt(s2), (double)EPSN);
        int best = (f2 > f1 || (f2 == f1 && c2 < c1)) ? c2 : c1;
        if (lane == 0) out[ASSIGN_OFF + pixq] = (float)best;
    }
}

extern "C" void kernel_launch(void* const* d_in, const int* in_sizes, int n_in,
                              void* d_out, int out_size, void* d_ws, size_t ws_size,
                              hipStream_t stream) {
    const float* qry   = (const float*)d_in[0];
    const float* sup_x = (const float*)d_in[1];
    const float* sup_y = (const float*)d_in[2];
    float* out = (float*)d_out;
    char* ws = (char*)d_ws;

    // workspace layout (~156.3 MB total)
    float* pooledT = (float*)ws;                       //  2 MB   [C_][P_]
    float* rnv     = pooledT + C_ * P_;                //  4 KB
    float* validf  = rnv + P_;                         //  4 KB
    float* rq      = validf + P_;                      //  256 KB [NPIX]
    short* Bph     = (short*)(rq + NPIX);              //  1 MB
    short* Bpl     = Bph + 64 * 1024 * 8;              //  1 MB
    short* Aph     = Bpl + 64 * 1024 * 8;              //  64 MB
    short* Apl     = Aph + (size_t)64 * NPIX * 8;      //  64 MB
    float* part    = (float*)(Apl + (size_t)64 * NPIX * 8);  // 24 MB

    pool_y_kernel<<<4, 256, 0, stream>>>(sup_y, out + GRID_OFF, validf);
    pool_x_kernel<<<B_ * C_ / 4, 256, 0, stream>>>(sup_x, pooledT);
    proto_rnorm_kernel<<<P_ / 4, 256, 0, stream>>>(pooledT, validf, rnv);
    pack_b_kernel<<<128, 256, 0, stream>>>(pooledT, Bph, Bpl);
    qsplit_kernel<<<1024, 256, 0, stream>>>(qry, Aph, Apl, rq);
    gemm_kernel<<<4096, 256, 0, stream>>>(Aph, Apl, Bph, Bpl, rnv, rq, part);
    merge_kernel<<<NPIX / 256, 256, 0, stream>>>(part, qry, pooledT, out);
}